// Round 7
// baseline (352.543 us; speedup 1.0000x reference)
//
#include <hip/hip_runtime.h>
#include <hip/hip_bf16.h>

// NeighborAwareLoss, round 7: single-variable experiment — replace the LDS
// read-modify-write (ds_read + v_add + ds_write, 2 DS ops/element) with
// ds_add_f32 (atomicAdd, unused return -> no-rtn form, 1 DS op/element).
// Load hoisting is preserved structurally by the explicit ping-pong groups
// (all of group g+1's loads issue in program order before group g's DS ops),
// so this isolates the ds_add instruction cost from rounds 1-3's confounds.
// Core: wave-per-row coalesced 1KB loads, private LDS slots acc[link][tid],
// width-16 shuffle epilogue. 6 blocks/CU.

constexpr int B_ROWS = 16384;
constexpr int T_TUN  = 4088;   // D*TPD
constexpr int D_DST  = 511;
constexpr int L_LNK  = 16;
constexpr int OCT    = 511;    // one demand per octet (dst = t>>3)
constexpr int BLK    = 256;
constexpr int WPB    = 4;      // waves (=rows) per block
constexpr int ITERS  = 16;     // ceil(4088 / 256)
constexpr int F4_PER_ROW = T_TUN / 4;   // 1022 float4s
constexpr float EPSF = 1e-8f;

__device__ __forceinline__
void load_group(int g, const float4* __restrict__ pr4, const float* __restrict__ dem,
                const unsigned int* packs, int lane,
                float4 pv[4], float dm[4], unsigned pk[4])
{
    #pragma unroll
    for (int k = 0; k < 4; ++k) {
        const int it  = g * 4 + k;
        const int idx = it * 64 + lane;                  // float4 index in row
        const int ci  = idx > (F4_PER_ROW - 1) ? (F4_PER_ROW - 1) : idx;
        const int oct = ci >> 1;
        pv[k] = pr4[ci];                                 // coalesced 1KB/wave
        const float dv = dem[oct];                       // coalesced, 2-way dup
        dm[k] = (idx <= (F4_PER_ROW - 1)) ? dv : 0.0f;   // zero OOB tail
        pk[k] = packs[oct];
    }
}

__device__ __forceinline__
void acc_group(float* acc, int tid, int half_sh,
               const float4 pv[4], const float dm[4], const unsigned pk[4])
{
    // Private slots (only this tid touches column tid) -> ds_add_f32 no-rtn.
    #pragma unroll
    for (int k = 0; k < 4; ++k) {
        const unsigned h = (pk[k] >> half_sh) & 0xFFFFu;
        const float d0 = dm[k];
        atomicAdd(&acc[((h      ) & 15) * BLK + tid], pv[k].x * d0);
        atomicAdd(&acc[((h >>  4) & 15) * BLK + tid], pv[k].y * d0);
        atomicAdd(&acc[((h >>  8) & 15) * BLK + tid], pv[k].z * d0);
        atomicAdd(&acc[((h >> 12)     ) * BLK + tid], pv[k].w * d0);
    }
}

__global__ __launch_bounds__(BLK, 6)
void nal_main(const float* __restrict__ pred,
              const float* __restrict__ demands,
              const float* __restrict__ nbr,
              const float* __restrict__ cap,
              const int*   __restrict__ t2l,
              double*      __restrict__ partials)
{
    __shared__ float acc[L_LNK * BLK];     // 16 KB, acc[link][tid]: bank = tid%32
    __shared__ unsigned int packs[OCT];    // 2 KB: 8x4-bit links per octet
    __shared__ float rowloss[WPB];

    const int tid  = threadIdx.x;
    const int wave = tid >> 6;
    const int lane = tid & 63;
    const int row  = blockIdx.x * WPB + wave;

    // Stage packed tunnel_to_link (row-invariant). 16KB from L2, overlapped.
    const int4* t2l4 = reinterpret_cast<const int4*>(t2l);
    for (int o = tid; o < OCT; o += BLK) {
        int4 a = t2l4[2 * o];
        int4 c = t2l4[2 * o + 1];
        packs[o] = (unsigned)a.x        | ((unsigned)a.y << 4)
                 | ((unsigned)a.z << 8) | ((unsigned)a.w << 12)
                 | ((unsigned)c.x << 16)| ((unsigned)c.y << 20)
                 | ((unsigned)c.z << 24)| ((unsigned)c.w << 28);
    }

    #pragma unroll
    for (int l = 0; l < L_LNK; ++l) acc[l * BLK + tid] = 0.0f;

    __syncthreads();

    // ---- Accumulation: 2-stage pipeline, groups of 4 iterations ----
    const float4* pr4 = reinterpret_cast<const float4*>(pred + (size_t)row * T_TUN);
    const float*  dem = demands + (size_t)row * D_DST;
    const int half_sh = (lane & 1) * 16;

    float4   pvA[4], pvB[4];
    float    dmA[4], dmB[4];
    unsigned pkA[4], pkB[4];

    load_group(0, pr4, dem, packs, lane, pvA, dmA, pkA);   // prologue
    load_group(1, pr4, dem, packs, lane, pvB, dmB, pkB);   // group1 in flight
    acc_group(acc, tid, half_sh, pvA, dmA, pkA);           // compute 0
    load_group(2, pr4, dem, packs, lane, pvA, dmA, pkA);   // group2 in flight
    acc_group(acc, tid, half_sh, pvB, dmB, pkB);           // compute 1
    load_group(3, pr4, dem, packs, lane, pvB, dmB, pkB);   // group3 in flight
    acc_group(acc, tid, half_sh, pvA, dmA, pkA);           // compute 2
    acc_group(acc, tid, half_sh, pvB, dmB, pkB);           // compute 3

    __syncthreads();

    // ---- Per-wave epilogue: reduce this wave's 64 columns per link ----
    {
        const int link = lane & 15;
        const int sub  = lane >> 4;                 // 0..3
        const int colbase = (wave << 6) + (sub << 4);
        float s = 0.0f;
        #pragma unroll
        for (int j = 0; j < 16; ++j) {
            const int jj = (j + link) & 15;         // diagonal: 2 lanes/bank
            s += acc[link * BLK + colbase + jj];
        }
        s += __shfl_xor(s, 16);                     // combine sub partials
        s += __shfl_xor(s, 32);
        const float lt = s;

        const float util = lt / (cap[link] + EPSF);

        float s_u = util;
        s_u += __shfl_xor(s_u, 1, 16); s_u += __shfl_xor(s_u, 2, 16);
        s_u += __shfl_xor(s_u, 4, 16); s_u += __shfl_xor(s_u, 8, 16);

        float mx = util;
        mx = fmaxf(mx, __shfl_xor(mx, 1, 16));
        mx = fmaxf(mx, __shfl_xor(mx, 2, 16));
        mx = fmaxf(mx, __shfl_xor(mx, 4, 16));
        mx = fmaxf(mx, __shfl_xor(mx, 8, 16));

        const float mean = s_u * (1.0f / 16.0f);
        const float d    = util - mean;
        float s_d2 = d * d;
        s_d2 += __shfl_xor(s_d2, 1, 16); s_d2 += __shfl_xor(s_d2, 2, 16);
        s_d2 += __shfl_xor(s_d2, 4, 16); s_d2 += __shfl_xor(s_d2, 8, 16);
        const float var = s_d2 * (1.0f / 15.0f);    // ddof=1

        float s_lt = lt;
        s_lt += __shfl_xor(s_lt, 1, 16); s_lt += __shfl_xor(s_lt, 2, 16);
        s_lt += __shfl_xor(s_lt, 4, 16); s_lt += __shfl_xor(s_lt, 8, 16);

        const float nl = nbr[(size_t)row * L_LNK + link];
        float s_nl = nl;
        s_nl += __shfl_xor(s_nl, 1, 16); s_nl += __shfl_xor(s_nl, 2, 16);
        s_nl += __shfl_xor(s_nl, 4, 16); s_nl += __shfl_xor(s_nl, 8, 16);

        float c = (lt / (s_lt + EPSF)) * (nl / (s_nl + EPSF));
        c += __shfl_xor(c, 1, 16); c += __shfl_xor(c, 2, 16);
        c += __shfl_xor(c, 4, 16); c += __shfl_xor(c, 8, 16);

        if (lane == 0) rowloss[wave] = var + 0.5f * mx + 0.3f * c;
    }

    __syncthreads();

    if (tid == 0) {
        double s = 0.0;
        #pragma unroll
        for (int w = 0; w < WPB; ++w) s += (double)rowloss[w];
        partials[blockIdx.x] = s;
    }
}

__global__ __launch_bounds__(BLK, 1)
void nal_reduce(const double* __restrict__ partials, float* __restrict__ out, int n)
{
    __shared__ double sh[BLK];
    int tid = threadIdx.x;
    double s = 0.0;
    for (int i = tid; i < n; i += BLK) s += partials[i];
    sh[tid] = s;
    __syncthreads();
    for (int off = BLK / 2; off > 0; off >>= 1) {
        if (tid < off) sh[tid] += sh[tid + off];
        __syncthreads();
    }
    if (tid == 0) out[0] = (float)(sh[0] / (double)B_ROWS);
}

extern "C" void kernel_launch(void* const* d_in, const int* in_sizes, int n_in,
                              void* d_out, int out_size, void* d_ws, size_t ws_size,
                              hipStream_t stream)
{
    const float* pred    = (const float*)d_in[0];   // (B, T)
    const float* demands = (const float*)d_in[1];   // (B, D)
    const float* nbr     = (const float*)d_in[2];   // (B, L)
    const float* cap     = (const float*)d_in[3];   // (L,)
    const int*   t2l     = (const int*)d_in[4];     // (T,)
    // d_in[5] = dst_of_tunnel == arange(T)//8, implicit.

    const int grid = B_ROWS / WPB;   // 4096 blocks, 4 rows (waves) each
    double* partials = (double*)d_ws; // 32 KB

    nal_main<<<grid, BLK, 0, stream>>>(pred, demands, nbr, cap, t2l, partials);
    nal_reduce<<<1, BLK, 0, stream>>>(partials, (float*)d_out, grid);
}

// Round 8
// 259.469 us; speedup vs baseline: 1.3587x; 1.3587x over previous
//
#include <hip/hip_runtime.h>
#include <hip/hip_bf16.h>

// NeighborAwareLoss, round 8: round-6 core (56us: wave-per-row coalesced 1KB
// loads, private LDS slots acc[link][tid] with plain RMW — NOT ds_add_f32,
// which round 7 proved is 6x slower — width-16 shuffle epilogue) + fused
// final reduction via last-block pattern (removes the serialized nal_reduce
// launch, ~3-5us). Counter in d_ws zeroed per call via hipMemsetAsync.

constexpr int B_ROWS = 16384;
constexpr int T_TUN  = 4088;   // D*TPD
constexpr int D_DST  = 511;
constexpr int L_LNK  = 16;
constexpr int OCT    = 511;    // one demand per octet (dst = t>>3)
constexpr int BLK    = 256;
constexpr int WPB    = 4;      // waves (=rows) per block
constexpr int ITERS  = 16;     // ceil(4088 / 256)
constexpr int F4_PER_ROW = T_TUN / 4;   // 1022 float4s
constexpr int GRID   = B_ROWS / WPB;    // 4096 blocks
constexpr float EPSF = 1e-8f;

__device__ __forceinline__
void load_group(int g, const float4* __restrict__ pr4, const float* __restrict__ dem,
                const unsigned int* packs, int lane,
                float4 pv[4], float dm[4], unsigned pk[4])
{
    #pragma unroll
    for (int k = 0; k < 4; ++k) {
        const int it  = g * 4 + k;
        const int idx = it * 64 + lane;                  // float4 index in row
        const int ci  = idx > (F4_PER_ROW - 1) ? (F4_PER_ROW - 1) : idx;
        const int oct = ci >> 1;
        pv[k] = pr4[ci];                                 // coalesced 1KB/wave
        const float dv = dem[oct];                       // coalesced, 2-way dup
        dm[k] = (idx <= (F4_PER_ROW - 1)) ? dv : 0.0f;   // zero OOB tail
        pk[k] = packs[oct];
    }
}

__device__ __forceinline__
void acc_group(float* acc, int tid, int half_sh,
               const float4 pv[4], const float dm[4], const unsigned pk[4])
{
    // Private slots (only this tid touches column tid): plain LDS RMW.
    // NOTE: do NOT use atomicAdd here — round 7 measured ds_add_f32 at ~6x
    // the cost of ds_read+v_fmac+ds_write on gfx950 (352us vs 56us kernel).
    #pragma unroll
    for (int k = 0; k < 4; ++k) {
        const unsigned h = (pk[k] >> half_sh) & 0xFFFFu;
        const float d0 = dm[k];
        acc[((h      ) & 15) * BLK + tid] += pv[k].x * d0;
        acc[((h >>  4) & 15) * BLK + tid] += pv[k].y * d0;
        acc[((h >>  8) & 15) * BLK + tid] += pv[k].z * d0;
        acc[((h >> 12)     ) * BLK + tid] += pv[k].w * d0;
    }
}

__global__ __launch_bounds__(BLK, 6)
void nal_main(const float* __restrict__ pred,
              const float* __restrict__ demands,
              const float* __restrict__ nbr,
              const float* __restrict__ cap,
              const int*   __restrict__ t2l,
              double*      __restrict__ partials,
              unsigned int* __restrict__ counter,
              float*       __restrict__ out)
{
    __shared__ float acc[L_LNK * BLK];     // 16 KB, acc[link][tid]: bank = tid%32
    __shared__ unsigned int packs[OCT];    // 2 KB: 8x4-bit links per octet
    __shared__ float rowloss[WPB];
    __shared__ int is_last;
    __shared__ double sh[BLK];

    const int tid  = threadIdx.x;
    const int wave = tid >> 6;
    const int lane = tid & 63;
    const int row  = blockIdx.x * WPB + wave;

    // Stage packed tunnel_to_link (row-invariant). 16KB from L2, overlapped.
    const int4* t2l4 = reinterpret_cast<const int4*>(t2l);
    for (int o = tid; o < OCT; o += BLK) {
        int4 a = t2l4[2 * o];
        int4 c = t2l4[2 * o + 1];
        packs[o] = (unsigned)a.x        | ((unsigned)a.y << 4)
                 | ((unsigned)a.z << 8) | ((unsigned)a.w << 12)
                 | ((unsigned)c.x << 16)| ((unsigned)c.y << 20)
                 | ((unsigned)c.z << 24)| ((unsigned)c.w << 28);
    }

    #pragma unroll
    for (int l = 0; l < L_LNK; ++l) acc[l * BLK + tid] = 0.0f;

    __syncthreads();

    // ---- Accumulation: 2-stage pipeline, groups of 4 iterations ----
    const float4* pr4 = reinterpret_cast<const float4*>(pred + (size_t)row * T_TUN);
    const float*  dem = demands + (size_t)row * D_DST;
    const int half_sh = (lane & 1) * 16;

    float4   pvA[4], pvB[4];
    float    dmA[4], dmB[4];
    unsigned pkA[4], pkB[4];

    load_group(0, pr4, dem, packs, lane, pvA, dmA, pkA);
    load_group(1, pr4, dem, packs, lane, pvB, dmB, pkB);
    acc_group(acc, tid, half_sh, pvA, dmA, pkA);
    load_group(2, pr4, dem, packs, lane, pvA, dmA, pkA);
    acc_group(acc, tid, half_sh, pvB, dmB, pkB);
    load_group(3, pr4, dem, packs, lane, pvB, dmB, pkB);
    acc_group(acc, tid, half_sh, pvA, dmA, pkA);
    acc_group(acc, tid, half_sh, pvB, dmB, pkB);

    __syncthreads();

    // ---- Per-wave epilogue: reduce this wave's 64 columns per link ----
    {
        const int link = lane & 15;
        const int sub  = lane >> 4;                 // 0..3
        const int colbase = (wave << 6) + (sub << 4);
        float s = 0.0f;
        #pragma unroll
        for (int j = 0; j < 16; ++j) {
            const int jj = (j + link) & 15;         // diagonal: 2 lanes/bank
            s += acc[link * BLK + colbase + jj];
        }
        s += __shfl_xor(s, 16);                     // combine sub partials
        s += __shfl_xor(s, 32);
        const float lt = s;

        const float util = lt / (cap[link] + EPSF);

        float s_u = util;
        s_u += __shfl_xor(s_u, 1, 16); s_u += __shfl_xor(s_u, 2, 16);
        s_u += __shfl_xor(s_u, 4, 16); s_u += __shfl_xor(s_u, 8, 16);

        float mx = util;
        mx = fmaxf(mx, __shfl_xor(mx, 1, 16));
        mx = fmaxf(mx, __shfl_xor(mx, 2, 16));
        mx = fmaxf(mx, __shfl_xor(mx, 4, 16));
        mx = fmaxf(mx, __shfl_xor(mx, 8, 16));

        const float mean = s_u * (1.0f / 16.0f);
        const float d    = util - mean;
        float s_d2 = d * d;
        s_d2 += __shfl_xor(s_d2, 1, 16); s_d2 += __shfl_xor(s_d2, 2, 16);
        s_d2 += __shfl_xor(s_d2, 4, 16); s_d2 += __shfl_xor(s_d2, 8, 16);
        const float var = s_d2 * (1.0f / 15.0f);    // ddof=1

        float s_lt = lt;
        s_lt += __shfl_xor(s_lt, 1, 16); s_lt += __shfl_xor(s_lt, 2, 16);
        s_lt += __shfl_xor(s_lt, 4, 16); s_lt += __shfl_xor(s_lt, 8, 16);

        const float nl = nbr[(size_t)row * L_LNK + link];
        float s_nl = nl;
        s_nl += __shfl_xor(s_nl, 1, 16); s_nl += __shfl_xor(s_nl, 2, 16);
        s_nl += __shfl_xor(s_nl, 4, 16); s_nl += __shfl_xor(s_nl, 8, 16);

        float c = (lt / (s_lt + EPSF)) * (nl / (s_nl + EPSF));
        c += __shfl_xor(c, 1, 16); c += __shfl_xor(c, 2, 16);
        c += __shfl_xor(c, 4, 16); c += __shfl_xor(c, 8, 16);

        if (lane == 0) rowloss[wave] = var + 0.5f * mx + 0.3f * c;
    }

    __syncthreads();

    // ---- Publish partial; last-arriving block does the final reduce ----
    if (tid == 0) {
        double s = 0.0;
        #pragma unroll
        for (int w = 0; w < WPB; ++w) s += (double)rowloss[w];
        partials[blockIdx.x] = s;
        __threadfence();                                   // release partial
        unsigned old = atomicAdd(counter, 1u);             // device scope
        is_last = (old == (unsigned)(GRID - 1)) ? 1 : 0;
    }
    __syncthreads();

    if (is_last) {
        __threadfence();                                   // acquire partials
        volatile const double* vp = partials;
        double s = 0.0;
        for (int i = tid; i < GRID; i += BLK) s += vp[i];  // fixed order/thread
        sh[tid] = s;
        __syncthreads();
        for (int off = BLK / 2; off > 0; off >>= 1) {
            if (tid < off) sh[tid] += sh[tid + off];
            __syncthreads();
        }
        if (tid == 0) out[0] = (float)(sh[0] / (double)B_ROWS);
    }
}

extern "C" void kernel_launch(void* const* d_in, const int* in_sizes, int n_in,
                              void* d_out, int out_size, void* d_ws, size_t ws_size,
                              hipStream_t stream)
{
    const float* pred    = (const float*)d_in[0];   // (B, T)
    const float* demands = (const float*)d_in[1];   // (B, D)
    const float* nbr     = (const float*)d_in[2];   // (B, L)
    const float* cap     = (const float*)d_in[3];   // (L,)
    const int*   t2l     = (const int*)d_in[4];     // (T,)
    // d_in[5] = dst_of_tunnel == arange(T)//8, implicit.

    double*       partials = (double*)d_ws;                       // 32 KB
    unsigned int* counter  = (unsigned int*)((char*)d_ws + 32768);

    // Zero the arrival counter each call (graph-capture-safe async memset).
    hipMemsetAsync(counter, 0, sizeof(unsigned int), stream);

    nal_main<<<GRID, BLK, 0, stream>>>(pred, demands, nbr, cap, t2l,
                                       partials, counter, (float*)d_out);
}

// Round 9
// 55.856 us; speedup vs baseline: 6.3117x; 4.6453x over previous
//
#include <hip/hip_runtime.h>
#include <hip/hip_bf16.h>

// NeighborAwareLoss, round 9: exact revert to the round-6 kernel (56.0 us,
// reproduced twice). Session-established facts baked in as comments:
//  - LDS slots acc[link][tid] are thread-private -> plain RMW. ds_add_f32
//    (atomicAdd) is ~6x slower here (R7: 352us vs 56us).
//  - Fusing the final reduce via threadfence+global-atomic last-block slowed
//    the whole main loop 6x (R8: 311us dispatches). Keep the separate tiny
//    reduce kernel (~5us serialized, fixed cost).
//  - Main dispatch runs at ~5.9 TB/s aggregate (149MB HBM + ~153MB L3) =
//    94% of the 6.29 TB/s copy ceiling -> memory-service roofline.
// Core: wave-per-row coalesced 1KB loads, packed 4-bit link map in LDS,
// 2-stage ping-pong load pipeline, width-16 shuffle epilogue, 6 blocks/CU.

constexpr int B_ROWS = 16384;
constexpr int T_TUN  = 4088;   // D*TPD
constexpr int D_DST  = 511;
constexpr int L_LNK  = 16;
constexpr int OCT    = 511;    // one demand per octet (dst = t>>3)
constexpr int BLK    = 256;
constexpr int WPB    = 4;      // waves (=rows) per block
constexpr int ITERS  = 16;     // ceil(4088 / 256)
constexpr int F4_PER_ROW = T_TUN / 4;   // 1022 float4s
constexpr float EPSF = 1e-8f;

__device__ __forceinline__
void load_group(int g, const float4* __restrict__ pr4, const float* __restrict__ dem,
                const unsigned int* packs, int lane,
                float4 pv[4], float dm[4], unsigned pk[4])
{
    #pragma unroll
    for (int k = 0; k < 4; ++k) {
        const int it  = g * 4 + k;
        const int idx = it * 64 + lane;                  // float4 index in row
        const int ci  = idx > (F4_PER_ROW - 1) ? (F4_PER_ROW - 1) : idx;
        const int oct = ci >> 1;
        pv[k] = pr4[ci];                                 // coalesced 1KB/wave
        const float dv = dem[oct];                       // coalesced, 2-way dup
        dm[k] = (idx <= (F4_PER_ROW - 1)) ? dv : 0.0f;   // zero OOB tail
        pk[k] = packs[oct];
    }
}

__device__ __forceinline__
void acc_group(float* acc, int tid, int half_sh,
               const float4 pv[4], const float dm[4], const unsigned pk[4])
{
    // Private slots (only this tid touches column tid): plain LDS RMW.
    #pragma unroll
    for (int k = 0; k < 4; ++k) {
        const unsigned h = (pk[k] >> half_sh) & 0xFFFFu;
        const float d0 = dm[k];
        acc[((h      ) & 15) * BLK + tid] += pv[k].x * d0;
        acc[((h >>  4) & 15) * BLK + tid] += pv[k].y * d0;
        acc[((h >>  8) & 15) * BLK + tid] += pv[k].z * d0;
        acc[((h >> 12)     ) * BLK + tid] += pv[k].w * d0;
    }
}

__global__ __launch_bounds__(BLK, 6)
void nal_main(const float* __restrict__ pred,
              const float* __restrict__ demands,
              const float* __restrict__ nbr,
              const float* __restrict__ cap,
              const int*   __restrict__ t2l,
              double*      __restrict__ partials)
{
    __shared__ float acc[L_LNK * BLK];     // 16 KB, acc[link][tid]: bank = tid%32
    __shared__ unsigned int packs[OCT];    // 2 KB: 8x4-bit links per octet
    __shared__ float rowloss[WPB];

    const int tid  = threadIdx.x;
    const int wave = tid >> 6;
    const int lane = tid & 63;
    const int row  = blockIdx.x * WPB + wave;

    // Stage packed tunnel_to_link (row-invariant). 16KB from L2, overlapped.
    const int4* t2l4 = reinterpret_cast<const int4*>(t2l);
    for (int o = tid; o < OCT; o += BLK) {
        int4 a = t2l4[2 * o];
        int4 c = t2l4[2 * o + 1];
        packs[o] = (unsigned)a.x        | ((unsigned)a.y << 4)
                 | ((unsigned)a.z << 8) | ((unsigned)a.w << 12)
                 | ((unsigned)c.x << 16)| ((unsigned)c.y << 20)
                 | ((unsigned)c.z << 24)| ((unsigned)c.w << 28);
    }

    #pragma unroll
    for (int l = 0; l < L_LNK; ++l) acc[l * BLK + tid] = 0.0f;

    __syncthreads();

    // ---- Accumulation: 2-stage pipeline, groups of 4 iterations ----
    const float4* pr4 = reinterpret_cast<const float4*>(pred + (size_t)row * T_TUN);
    const float*  dem = demands + (size_t)row * D_DST;
    const int half_sh = (lane & 1) * 16;

    float4   pvA[4], pvB[4];
    float    dmA[4], dmB[4];
    unsigned pkA[4], pkB[4];

    load_group(0, pr4, dem, packs, lane, pvA, dmA, pkA);   // prologue
    load_group(1, pr4, dem, packs, lane, pvB, dmB, pkB);   // group1 in flight
    acc_group(acc, tid, half_sh, pvA, dmA, pkA);           // compute 0
    load_group(2, pr4, dem, packs, lane, pvA, dmA, pkA);   // group2 in flight
    acc_group(acc, tid, half_sh, pvB, dmB, pkB);           // compute 1
    load_group(3, pr4, dem, packs, lane, pvB, dmB, pkB);   // group3 in flight
    acc_group(acc, tid, half_sh, pvA, dmA, pkA);           // compute 2
    acc_group(acc, tid, half_sh, pvB, dmB, pkB);           // compute 3

    __syncthreads();

    // ---- Per-wave epilogue: reduce this wave's 64 columns per link ----
    {
        const int link = lane & 15;
        const int sub  = lane >> 4;                 // 0..3
        const int colbase = (wave << 6) + (sub << 4);
        float s = 0.0f;
        #pragma unroll
        for (int j = 0; j < 16; ++j) {
            const int jj = (j + link) & 15;         // diagonal: 2 lanes/bank
            s += acc[link * BLK + colbase + jj];
        }
        s += __shfl_xor(s, 16);                     // combine sub partials
        s += __shfl_xor(s, 32);
        const float lt = s;

        const float util = lt / (cap[link] + EPSF);

        float s_u = util;
        s_u += __shfl_xor(s_u, 1, 16); s_u += __shfl_xor(s_u, 2, 16);
        s_u += __shfl_xor(s_u, 4, 16); s_u += __shfl_xor(s_u, 8, 16);

        float mx = util;
        mx = fmaxf(mx, __shfl_xor(mx, 1, 16));
        mx = fmaxf(mx, __shfl_xor(mx, 2, 16));
        mx = fmaxf(mx, __shfl_xor(mx, 4, 16));
        mx = fmaxf(mx, __shfl_xor(mx, 8, 16));

        const float mean = s_u * (1.0f / 16.0f);
        const float d    = util - mean;
        float s_d2 = d * d;
        s_d2 += __shfl_xor(s_d2, 1, 16); s_d2 += __shfl_xor(s_d2, 2, 16);
        s_d2 += __shfl_xor(s_d2, 4, 16); s_d2 += __shfl_xor(s_d2, 8, 16);
        const float var = s_d2 * (1.0f / 15.0f);    // ddof=1

        float s_lt = lt;
        s_lt += __shfl_xor(s_lt, 1, 16); s_lt += __shfl_xor(s_lt, 2, 16);
        s_lt += __shfl_xor(s_lt, 4, 16); s_lt += __shfl_xor(s_lt, 8, 16);

        const float nl = nbr[(size_t)row * L_LNK + link];
        float s_nl = nl;
        s_nl += __shfl_xor(s_nl, 1, 16); s_nl += __shfl_xor(s_nl, 2, 16);
        s_nl += __shfl_xor(s_nl, 4, 16); s_nl += __shfl_xor(s_nl, 8, 16);

        float c = (lt / (s_lt + EPSF)) * (nl / (s_nl + EPSF));
        c += __shfl_xor(c, 1, 16); c += __shfl_xor(c, 2, 16);
        c += __shfl_xor(c, 4, 16); c += __shfl_xor(c, 8, 16);

        if (lane == 0) rowloss[wave] = var + 0.5f * mx + 0.3f * c;
    }

    __syncthreads();

    if (tid == 0) {
        double s = 0.0;
        #pragma unroll
        for (int w = 0; w < WPB; ++w) s += (double)rowloss[w];
        partials[blockIdx.x] = s;
    }
}

__global__ __launch_bounds__(BLK, 1)
void nal_reduce(const double* __restrict__ partials, float* __restrict__ out, int n)
{
    __shared__ double sh[BLK];
    int tid = threadIdx.x;
    double s = 0.0;
    for (int i = tid; i < n; i += BLK) s += partials[i];
    sh[tid] = s;
    __syncthreads();
    for (int off = BLK / 2; off > 0; off >>= 1) {
        if (tid < off) sh[tid] += sh[tid + off];
        __syncthreads();
    }
    if (tid == 0) out[0] = (float)(sh[0] / (double)B_ROWS);
}

extern "C" void kernel_launch(void* const* d_in, const int* in_sizes, int n_in,
                              void* d_out, int out_size, void* d_ws, size_t ws_size,
                              hipStream_t stream)
{
    const float* pred    = (const float*)d_in[0];   // (B, T)
    const float* demands = (const float*)d_in[1];   // (B, D)
    const float* nbr     = (const float*)d_in[2];   // (B, L)
    const float* cap     = (const float*)d_in[3];   // (L,)
    const int*   t2l     = (const int*)d_in[4];     // (T,)
    // d_in[5] = dst_of_tunnel == arange(T)//8, implicit.

    const int grid = B_ROWS / WPB;   // 4096 blocks, 4 rows (waves) each
    double* partials = (double*)d_ws; // 32 KB

    nal_main<<<grid, BLK, 0, stream>>>(pred, demands, nbr, cap, t2l, partials);
    nal_reduce<<<1, BLK, 0, stream>>>(partials, (float*)d_out, grid);
}